// Round 8
// baseline (1544.113 us; speedup 1.0000x reference)
//
#include <hip/hip_runtime.h>
#include <hip/hip_bf16.h>
#include <stdint.h>

// Problem constants (from reference)
#define IN_F 4096
#define OUT_F 11008
#define M_ROWS 8192              // 4 * 2048
#define NIG 512                  // IN_FEATURES / IN_GROUP(8)
#define CBSZ 256

typedef _Float16 f16x8 __attribute__((ext_vector_type(8)));
typedef float f32x4 __attribute__((ext_vector_type(4)));

// ---------------------------------------------------------------------------
// Kernel 1: dequantize W (UNSCALED: scales applied in GEMM epilogue in fp32).
// ---------------------------------------------------------------------------
__global__ __launch_bounds__(256) void dequant_w_kernel(
    const int* __restrict__ codes, const float* __restrict__ cbs,
    _Float16* __restrict__ W)
{
  const int idx = blockIdx.x * 256 + threadIdx.x;   // o*512 + g (exact grid)
  const int2 c = ((const int2*)codes)[idx];
  const float4* e0 = (const float4*)(cbs + (size_t)c.x * 8);
  const float4* e1 = (const float4*)(cbs + (size_t)CBSZ * 8 + (size_t)c.y * 8);
  const float4 a0 = e0[0], a1 = e0[1];
  const float4 b0 = e1[0], b1 = e1[1];
  f16x8 w;
  w[0] = (_Float16)(a0.x + b0.x);
  w[1] = (_Float16)(a0.y + b0.y);
  w[2] = (_Float16)(a0.z + b0.z);
  w[3] = (_Float16)(a0.w + b0.w);
  w[4] = (_Float16)(a1.x + b1.x);
  w[5] = (_Float16)(a1.y + b1.y);
  w[6] = (_Float16)(a1.z + b1.z);
  w[7] = (_Float16)(a1.w + b1.w);
  *(f16x8*)(W + (size_t)idx * 8) = w;
}

// ---------------------------------------------------------------------------
// Kernel 2: x fp32 -> f16, 8 elems/thread, vectorized.
// ---------------------------------------------------------------------------
__global__ __launch_bounds__(256) void convert_x_kernel(
    const float* __restrict__ x, _Float16* __restrict__ X)
{
  const size_t i = ((size_t)blockIdx.x * 256 + threadIdx.x) * 8;
  const float4 a = *(const float4*)(x + i);
  const float4 b = *(const float4*)(x + i + 4);
  f16x8 v;
  v[0] = (_Float16)a.x; v[1] = (_Float16)a.y;
  v[2] = (_Float16)a.z; v[3] = (_Float16)a.w;
  v[4] = (_Float16)b.x; v[5] = (_Float16)b.y;
  v[6] = (_Float16)b.z; v[7] = (_Float16)b.w;
  *(f16x8*)(X + i) = v;
}

// ---------------------------------------------------------------------------
// Kernel 3: 256x256x64 f16 GEMM — 4-phase modulo pipeline, 16-MFMA clusters.
// 512 threads = 8 waves (2M x 4N); per-wave output 128x64 (8x4 16x16 frags).
// LDS: 2 x (A [256][64] | B [256][64]) f16 = 128 KB. Bank swizzle (verified
// 0-conflict r4): chunk_lds = chunk ^ (row&7); read applies XOR, staging
// pre-permutes the GLOBAL source column, LDS dest stays linear.
//
// Per tile t (4 phases, ONE barrier each; 16 MFMA each; reads feed the NEXT
// phase's MFMA so LDS streams concurrently with matrix work):
//   p1: read bh(t)[4]          G1 = al(t)xbl(t)        (al,bl read p3/p4 t-1)
//   p2: read ah(t)[8]          G2 = al(t)xbh(t)        gate vmcnt(2)
//   p3: stage B(t+2)->bufT-B   read al(t+1)[8] (bufN)  G3 = ah x bh   gate vmcnt(4)
//   p4: stage A(t+2)->bufT-A   read bl(t+1)[4] (bufN)  G4 = ah x bl(t)
// Gate ledger (steady, per-thread outstanding: p3 +4, p4 +4, max 8):
//   end-p2 vmcnt(2): all but 2 done -> B(t+1) all + A(t+1){A0,A2} landed
//     => p3's al(t+1) reads and p4's bl(t+1) reads and p1(t+1)'s bh safe.
//   end-p3 vmcnt(4): all but B(t+2) done -> A(t+1){A1,A3} landed
//     => p2(t+1)'s ah reads safe.  vmcnt hits 0 only at the tile-62 edge.
// WAR: each stage lands >= 1 barrier after the last ds_read of that region
// retired (B-region free after end-p2 BAR; A-region free after end-p3 BAR).
// Only bl is double-generation (used at G4(t) while bl(t+1) is read).
// ---------------------------------------------------------------------------
#define BM 256
#define BN 256
#define BK 64
#define NKT (IN_F / BK)          // 64
#define GRID_MT (M_ROWS / BM)    // 32
#define GRID_NT (OUT_F / BN)     // 43

__global__ __launch_bounds__(512, 2) void gemm_pipe(
    const _Float16* __restrict__ X, const _Float16* __restrict__ Wd,
    const float* __restrict__ scales, const float* __restrict__ bias,
    float* __restrict__ out)
{
  __shared__ char smem[131072];  // [2 bufs][A 32KB | B 32KB]

  // T1: XCD swizzle; nwg = 1376 % 8 == 0 -> simple form bijective
  const int cpx = (GRID_MT * GRID_NT) >> 3;        // 172
  const int wg = (blockIdx.x & 7) * cpx + (blockIdx.x >> 3);
  const int mt = wg & (GRID_MT - 1), nt = wg >> 5; // m-inner: same B-panel per XCD
  const int m0 = mt * BM, n0 = nt * BN;

  const int t_ = threadIdx.x;
  const int wave = t_ >> 6, lane = t_ & 63;
  const int wm = wave >> 2, wn = wave & 3;
  const int r16 = lane & 15;
  const int q = lane >> 4;                         // 16B piece within 64B k-half
  const int sw = r16 & 7;                          // row&7 (rows offset by mult of 16)
  const int c0 = ((q ^ sw) << 4);                  // swizzled chunk byte, k-half 0
  const int c1 = (((4 | q) ^ sw) << 4);            // swizzled chunk byte, k-half 1

  // Staging: thread t's 16B lands at linear LDS byte (call*8192 + t*16)
  //   -> row = call*64 + (t>>3), chunk_lds = t&7; logical chunk = (t&7)^((t>>3)&7)
  const int s_row0 = t_ >> 3;
  const int s_col  = (((t_ & 7) ^ ((t_ >> 3) & 7)) << 3);
  const _Float16* asrc = X  + (size_t)(m0 + s_row0) * IN_F + s_col;
  const _Float16* bsrc = Wd + (size_t)(n0 + s_row0) * IN_F + s_col;
  const int s_dst = wave * 1024;                   // wave-uniform; HW adds lane*16

  f32x4 acc[8][4] = {};
  // Fragment registers. bl double-generation (G4(t) overlaps bl(t+1) read).
  f16x8 al0[4], al1[4], ah0[4], ah1[4];
  f16x8 bl0[2][2], bl1[2][2], bh0[2], bh1[2];

#define GLD(gsrc, ldst) __builtin_amdgcn_global_load_lds(                     \
    (const __attribute__((address_space(1))) void*)(gsrc),                    \
    (__attribute__((address_space(3))) void*)(ldst), 16, 0, 0)
#define STAGE_A(kt, bufc, i) GLD(asrc + (size_t)(kt) * BK + (size_t)(i) * 64 * IN_F, \
    smem + (bufc) * 65536 + (i) * 8192 + s_dst)
#define STAGE_B(kt, bufc, i) GLD(bsrc + (size_t)(kt) * BK + (size_t)(i) * 64 * IN_F, \
    smem + (bufc) * 65536 + 32768 + (i) * 8192 + s_dst)

#define RD_A(bufp, mm, cc) (*(const f16x8*)((bufp) + ((wm * 128 + (mm) * 16 + r16) << 7) + (cc)))
#define RD_B(bufp, nn, cc) (*(const f16x8*)((bufp) + 32768 + ((wn * 64 + (nn) * 16 + r16) << 7) + (cc)))

#define BAR   __builtin_amdgcn_s_barrier()
#define PRIO1 __builtin_amdgcn_s_setprio(1)
#define PRIO0 __builtin_amdgcn_s_setprio(0)
#define VM8 asm volatile("s_waitcnt vmcnt(8)" ::: "memory")
#define VM4 asm volatile("s_waitcnt vmcnt(4)" ::: "memory")
#define VM2 asm volatile("s_waitcnt vmcnt(2)" ::: "memory")
#define VM0 asm volatile("s_waitcnt vmcnt(0)" ::: "memory")

// 8-MFMA group: 4 m-frags x 2 n-frags into acc[MO..][NO..]
#define MG(AF, BF, MO, NO)                                                    \
    _Pragma("unroll")                                                         \
    for (int m = 0; m < 4; ++m)                                               \
      _Pragma("unroll")                                                       \
      for (int n = 0; n < 2; ++n)                                             \
        acc[(MO) + m][(NO) + n] = __builtin_amdgcn_mfma_f32_16x16x32_f16(     \
            AF[m], BF[n], acc[(MO) + m][(NO) + n], 0, 0, 0)

// One K-tile, 4 phases. P: parity literal. SB: stage B(t+2). SA: stage A(t+2).
// GP2: 1 -> vmcnt(2) at end-p2. GP3: 2 -> vmcnt(4), 0 -> vmcnt(0), -1 -> none.
#define TILE4(P, tt, SB, SA, GP2, GP3) do {                                   \
    char* bufT = smem + (P) * 65536;                                          \
    char* bufN = smem + (1 - (P)) * 65536;                                    \
    /* p1: read bh(t); G1 = al(t) x bl(t), both k-halves (16 MFMA) */         \
    _Pragma("unroll")                                                         \
    for (int n = 0; n < 2; ++n) { bh0[n] = RD_B(bufT, 2 + n, c0);             \
                                  bh1[n] = RD_B(bufT, 2 + n, c1); }           \
    PRIO1; MG(al0, bl0[P], 0, 0); MG(al1, bl1[P], 0, 0); PRIO0; BAR;          \
    /* p2: read ah(t); G2 = al x bh */                                        \
    _Pragma("unroll")                                                         \
    for (int m = 0; m < 4; ++m) { ah0[m] = RD_A(bufT, 4 + m, c0);             \
                                  ah1[m] = RD_A(bufT, 4 + m, c1); }           \
    PRIO1; MG(al0, bh0, 0, 2); MG(al1, bh1, 0, 2); PRIO0;                     \
    if (GP2) { VM2; }                                                         \
    BAR;                                                                      \
    /* p3: stage B(t+2)->bufT-B; read al(t+1) from bufN; G3 = ah x bh */      \
    if (SB) { STAGE_B((tt) + 2, P, 0); STAGE_B((tt) + 2, P, 1);               \
              STAGE_B((tt) + 2, P, 2); STAGE_B((tt) + 2, P, 3); }             \
    _Pragma("unroll")                                                         \
    for (int m = 0; m < 4; ++m) { al0[m] = RD_A(bufN, m, c0);                 \
                                  al1[m] = RD_A(bufN, m, c1); }               \
    PRIO1; MG(ah0, bh0, 4, 2); MG(ah1, bh1, 4, 2); PRIO0;                     \
    if ((GP3) == 2) { VM4; }                                                  \
    if ((GP3) == 0) { VM0; }                                                  \
    BAR;                                                                      \
    /* p4: stage A(t+2)->bufT-A (al-feeding calls 0,2 first); read bl(t+1);   \
       G4 = ah x bl(t) */                                                     \
    if (SA) { STAGE_A((tt) + 2, P, 0); STAGE_A((tt) + 2, P, 2);               \
              STAGE_A((tt) + 2, P, 1); STAGE_A((tt) + 2, P, 3); }             \
    _Pragma("unroll")                                                         \
    for (int n = 0; n < 2; ++n) { bl0[1 - (P)][n] = RD_B(bufN, n, c0);        \
                                  bl1[1 - (P)][n] = RD_B(bufN, n, c1); }      \
    PRIO1; MG(ah0, bl0[P], 4, 0); MG(ah1, bl1[P], 4, 0); PRIO0; BAR;          \
  } while (0)

  // ---- Prologue: tile0 (8 calls) + B(1) [≡p3(-1)] + A(1) [≡p4(-1)]
  {
    _Pragma("unroll")
    for (int i = 0; i < 4; ++i) { STAGE_A(0, 0, i); }
    _Pragma("unroll")
    for (int i = 0; i < 4; ++i) { STAGE_B(0, 0, i); }
    _Pragma("unroll")
    for (int i = 0; i < 4; ++i) { STAGE_B(1, 1, i); }
    STAGE_A(1, 1, 0); STAGE_A(1, 1, 2); STAGE_A(1, 1, 1); STAGE_A(1, 1, 3);
    VM8;                                   // tile0's 8 landed; 8 still in flight
    BAR;
    // Preload what p1(0) consumes (normally read at p3/p4 of t-1):
    char* buf0p = smem;
    _Pragma("unroll")
    for (int m = 0; m < 4; ++m) { al0[m] = RD_A(buf0p, m, c0);
                                  al1[m] = RD_A(buf0p, m, c1); }
    _Pragma("unroll")
    for (int n = 0; n < 2; ++n) { bl0[0][n] = RD_B(buf0p, n, c0);
                                  bl1[0][n] = RD_B(buf0p, n, c1); }
  }

  // ---- Main loop: tiles 0..61 (full pipeline)
  #pragma unroll 1
  for (int t = 0; t < 62; t += 2) {
    TILE4(0, t,     1, 1, 1, 2);
    TILE4(1, t + 1, 1, 1, 1, 2);
  }
  // ---- Tail: tile 62 (no stages; drain A(63) remnants at p3), tile 63
  // (no stages/gates; its p3/p4 prefetch-reads fetch stale LDS, dead values)
  TILE4(0, 62, 0, 0, 1, 0);
  TILE4(1, 63, 0, 0, 0, -1);

  // Epilogue: acc * scales[col] + bias[col], fp32.
  // C/D frag: col = lane&15, row = (lane>>4)*4 + reg (m89-verified).
  const int crow = (lane >> 4) << 2;
  #pragma unroll
  for (int nf = 0; nf < 4; ++nf) {
    const int col = n0 + wn * 64 + nf * 16 + r16;
    const float s = scales[col];
    const float bb = bias[col];
    #pragma unroll
    for (int mf = 0; mf < 8; ++mf) {
      const int rb = m0 + wm * 128 + mf * 16 + crow;
      #pragma unroll
      for (int r = 0; r < 4; ++r)
        out[(size_t)(rb + r) * OUT_F + col] = acc[mf][nf][r] * s + bb;
    }
  }
#undef TILE4
#undef MG
#undef RD_A
#undef RD_B
#undef STAGE_A
#undef STAGE_B
#undef GLD
}

// ---------------------------------------------------------------------------
// Fallback (only if ws too small): correct but slow fp32 path.
// ---------------------------------------------------------------------------
__global__ __launch_bounds__(256) void naive_kernel(
    const float* __restrict__ x, const int* __restrict__ codes,
    const float* __restrict__ cbs, const float* __restrict__ scales,
    const float* __restrict__ bias, float* __restrict__ out)
{
  __shared__ float xrow[IN_F];
  const int m = blockIdx.x;
  for (int i = threadIdx.x; i < IN_F; i += 256)
    xrow[i] = x[(size_t)m * IN_F + i];
  __syncthreads();
  for (int o = threadIdx.x; o < OUT_F; o += 256) {
    float acc = 0.f;
    const int2* crow = (const int2*)codes + (size_t)o * NIG;
    for (int g = 0; g < NIG; ++g) {
      const int2 c = crow[g];
      const float* e0 = cbs + (size_t)c.x * 8;
      const float* e1 = cbs + (size_t)CBSZ * 8 + (size_t)c.y * 8;
      const float* xr = xrow + g * 8;
      #pragma unroll
      for (int j = 0; j < 8; ++j) acc += (e0[j] + e1[j]) * xr[j];
    }
    out[(size_t)m * OUT_F + o] = acc * scales[o] + bias[o];
  }
}

// ---------------------------------------------------------------------------
extern "C" void kernel_launch(void* const* d_in, const int* in_sizes, int n_in,
                              void* d_out, int out_size, void* d_ws, size_t ws_size,
                              hipStream_t stream) {
  const float* x      = (const float*)d_in[0];
  const int*   codes  = (const int*)d_in[1];
  const float* cbs    = (const float*)d_in[2];
  const float* scales = (const float*)d_in[3];
  const float* bias   = (const float*)d_in[4];
  float* out = (float*)d_out;

  const size_t W_BYTES = (size_t)OUT_F * IN_F * sizeof(_Float16);  // 90.2 MB
  const size_t X_BYTES = (size_t)M_ROWS * IN_F * sizeof(_Float16); // 67.1 MB

  if (ws_size < W_BYTES + X_BYTES) {
    naive_kernel<<<M_ROWS, 256, 0, stream>>>(x, codes, cbs, scales, bias, out);
    return;
  }

  _Float16* W = (_Float16*)d_ws;
  _Float16* X = (_Float16*)((char*)d_ws + W_BYTES);

  dequant_w_kernel<<<(OUT_F * NIG) / 256, 256, 0, stream>>>(codes, cbs, W);
  convert_x_kernel<<<(M_ROWS * IN_F / 8) / 256, 256, 0, stream>>>(x, X);
  gemm_pipe<<<GRID_MT * GRID_NT, 512, 0, stream>>>(X, W, scales, bias, out);
}

// Round 9
// 818.036 us; speedup vs baseline: 1.8876x; 1.8876x over previous
//
#include <hip/hip_runtime.h>
#include <hip/hip_bf16.h>
#include <stdint.h>

// Problem constants (from reference)
#define IN_F 4096
#define OUT_F 11008
#define M_ROWS 8192              // 4 * 2048
#define NIG 512                  // IN_FEATURES / IN_GROUP(8)
#define CBSZ 256

typedef _Float16 f16x8 __attribute__((ext_vector_type(8)));
typedef float f32x4 __attribute__((ext_vector_type(4)));

// ---------------------------------------------------------------------------
// Kernel 1: dequantize W (UNSCALED: scales applied in GEMM epilogue in fp32).
// ---------------------------------------------------------------------------
__global__ __launch_bounds__(256) void dequant_w_kernel(
    const int* __restrict__ codes, const float* __restrict__ cbs,
    _Float16* __restrict__ W)
{
  const int idx = blockIdx.x * 256 + threadIdx.x;   // o*512 + g (exact grid)
  const int2 c = ((const int2*)codes)[idx];
  const float4* e0 = (const float4*)(cbs + (size_t)c.x * 8);
  const float4* e1 = (const float4*)(cbs + (size_t)CBSZ * 8 + (size_t)c.y * 8);
  const float4 a0 = e0[0], a1 = e0[1];
  const float4 b0 = e1[0], b1 = e1[1];
  f16x8 w;
  w[0] = (_Float16)(a0.x + b0.x);
  w[1] = (_Float16)(a0.y + b0.y);
  w[2] = (_Float16)(a0.z + b0.z);
  w[3] = (_Float16)(a0.w + b0.w);
  w[4] = (_Float16)(a1.x + b1.x);
  w[5] = (_Float16)(a1.y + b1.y);
  w[6] = (_Float16)(a1.z + b1.z);
  w[7] = (_Float16)(a1.w + b1.w);
  *(f16x8*)(W + (size_t)idx * 8) = w;
}

// ---------------------------------------------------------------------------
// Kernel 2: x fp32 -> f16, 8 elems/thread, vectorized.
// ---------------------------------------------------------------------------
__global__ __launch_bounds__(256) void convert_x_kernel(
    const float* __restrict__ x, _Float16* __restrict__ X)
{
  const size_t i = ((size_t)blockIdx.x * 256 + threadIdx.x) * 8;
  const float4 a = *(const float4*)(x + i);
  const float4 b = *(const float4*)(x + i + 4);
  f16x8 v;
  v[0] = (_Float16)a.x; v[1] = (_Float16)a.y;
  v[2] = (_Float16)a.z; v[3] = (_Float16)a.w;
  v[4] = (_Float16)b.x; v[5] = (_Float16)b.y;
  v[6] = (_Float16)b.z; v[7] = (_Float16)b.w;
  *(f16x8*)(X + i) = v;
}

// ---------------------------------------------------------------------------
// Kernel 3: 256x256x64 f16 GEMM — m201-style 4-phase, SAME-PHASE reads,
// spread staging (2 gload_lds per phase), counted vmcnt gates.
// 512 threads = 8 waves (2M x 4N); per-wave output 128x64 (8x4 16x16 frags).
// LDS: 2 x (A [256][64] | B [256][64]) f16 = 128 KB. Bank swizzle (verified
// 0-conflict r4): chunk_lds = chunk ^ (row&7); read applies XOR, staging
// pre-permutes the GLOBAL source column, LDS dest stays linear.
//
// REGISTER DISCIPLINE (r8 lesson): 8 waves -> 1 block/CU (LDS) -> 2 waves/SIMD
// -> HARD cap 256 unified regs/wave; acc=128 AGPR leaves 128 VGPR. Same-phase
// consumption keeps peak fragment live-set at 64 VGPR (no cross-tile carry).
//
// Per tile t (4 phases; stages write buf^1 for t+1; reads from buf):
//   ph1: stage A02(t+1) | read al(8),bl(4) | BAR | Q1=al*bl | BAR
//   ph2: stage B01(t+1) | read bh(4)       | BAR | Q2=al*bh | vmcnt(4) | BAR
//   ph3: stage B23(t+1) | read ah(8)       | BAR | Q3=ah*bh | BAR
//   ph4: stage A13(t+1) |                        | Q4=ah*bl | vmcnt(2) | BAR
// (A02 = A-calls {0,2} = rows 0-63,128-191 feeding al for both wm; A13 = ah
//  rows; B01/B23 = B row-halves — bl/bh readers span both, so both must land
//  before ph1/ph2 of the next tile.)
// Ledger (loads outstanding per thread; invariant entering ph1: 2 = {A13(t)}):
//   ph1 +2 -> 4; ph2 +2 -> 6; end-ph2 vmcnt(4) retires A13(t)  => ph3 ah safe
//   ph3 +2 -> 6; ph4 +2 -> 8; end-ph4 vmcnt(2) retires A02,B01,B23(t+1)
//     => ph1(t+1) al,bl and ph2(t+1) bh safe; invariant restored.
// vmcnt floor = 2 until tile 63 (edge: vmcnt(0) at end-ph2). WAR: stages hit
// buf^1 whose last reads finished a full tile (>=5 barriers) earlier.
// ---------------------------------------------------------------------------
#define BM 256
#define BN 256
#define BK 64
#define NKT (IN_F / BK)          // 64
#define GRID_MT (M_ROWS / BM)    // 32
#define GRID_NT (OUT_F / BN)     // 43

__global__ __launch_bounds__(512, 2) void gemm_pipe(
    const _Float16* __restrict__ X, const _Float16* __restrict__ Wd,
    const float* __restrict__ scales, const float* __restrict__ bias,
    float* __restrict__ out)
{
  __shared__ char smem[131072];  // [2 bufs][A 32KB | B 32KB]

  // T1: XCD swizzle; nwg = 1376 % 8 == 0 -> simple form bijective
  const int cpx = (GRID_MT * GRID_NT) >> 3;        // 172
  const int wg = (blockIdx.x & 7) * cpx + (blockIdx.x >> 3);
  const int mt = wg & (GRID_MT - 1), nt = wg >> 5; // m-inner: same B-panel per XCD
  const int m0 = mt * BM, n0 = nt * BN;

  const int t_ = threadIdx.x;
  const int wave = t_ >> 6, lane = t_ & 63;
  const int wm = wave >> 2, wn = wave & 3;
  const int r16 = lane & 15;
  const int q = lane >> 4;                         // 16B piece within 64B k-half
  const int sw = r16 & 7;                          // row&7 (rows offset by mult of 16)
  const int c0 = ((q ^ sw) << 4);                  // swizzled chunk byte, k-half 0
  const int c1 = (((4 | q) ^ sw) << 4);            // swizzled chunk byte, k-half 1

  // Staging: thread t's 16B lands at linear LDS byte (call*8192 + t*16)
  //   -> row = call*64 + (t>>3), chunk_lds = t&7; logical chunk = (t&7)^((t>>3)&7)
  const int s_row0 = t_ >> 3;
  const int s_col  = (((t_ & 7) ^ ((t_ >> 3) & 7)) << 3);
  const _Float16* asrc = X  + (size_t)(m0 + s_row0) * IN_F + s_col;
  const _Float16* bsrc = Wd + (size_t)(n0 + s_row0) * IN_F + s_col;
  const int s_dst = wave * 1024;                   // wave-uniform; HW adds lane*16

  f32x4 acc[8][4] = {};
  // Same-phase fragments: no cross-tile carry, peak live set 64 VGPR (ph2/ph3)
  f16x8 al0[4], al1[4], ah0[4], ah1[4], bl0[2], bl1[2], bh0[2], bh1[2];

#define GLD(gsrc, ldst) __builtin_amdgcn_global_load_lds(                     \
    (const __attribute__((address_space(1))) void*)(gsrc),                    \
    (__attribute__((address_space(3))) void*)(ldst), 16, 0, 0)
#define STAGE_A(kt, bufc, i) GLD(asrc + (size_t)(kt) * BK + (size_t)(i) * 64 * IN_F, \
    smem + (bufc) * 65536 + (i) * 8192 + s_dst)
#define STAGE_B(kt, bufc, i) GLD(bsrc + (size_t)(kt) * BK + (size_t)(i) * 64 * IN_F, \
    smem + (bufc) * 65536 + 32768 + (i) * 8192 + s_dst)

#define RD_A(bufp, mm, cc) (*(const f16x8*)((bufp) + ((wm * 128 + (mm) * 16 + r16) << 7) + (cc)))
#define RD_B(bufp, nn, cc) (*(const f16x8*)((bufp) + 32768 + ((wn * 64 + (nn) * 16 + r16) << 7) + (cc)))

#define BAR   __builtin_amdgcn_s_barrier()
#define PRIO1 __builtin_amdgcn_s_setprio(1)
#define PRIO0 __builtin_amdgcn_s_setprio(0)
#define VM4 asm volatile("s_waitcnt vmcnt(4)" ::: "memory")
#define VM2 asm volatile("s_waitcnt vmcnt(2)" ::: "memory")
#define VM0 asm volatile("s_waitcnt vmcnt(0)" ::: "memory")

// 8-MFMA group: 4 m-frags x 2 n-frags into acc[MO..][NO..]
#define MG(AF, BF, MO, NO)                                                    \
    _Pragma("unroll")                                                         \
    for (int m = 0; m < 4; ++m)                                               \
      _Pragma("unroll")                                                       \
      for (int n = 0; n < 2; ++n)                                             \
        acc[(MO) + m][(NO) + n] = __builtin_amdgcn_mfma_f32_16x16x32_f16(     \
            AF[m], BF[n], acc[(MO) + m][(NO) + n], 0, 0, 0)

// One K-tile, 4 phases, same-phase reads. P: parity. STG: stage t+1.
// G2: end-ph2 gate (4 normal, 0 tail). G4: end-ph4 gate (2 normal, -1 none).
#define TILE(P, tt, STG, G2, G4) do {                                         \
    const char* bufT = smem + (P) * 65536;                                    \
    /* ph1: stage A02(t+1); read al,bl; Q1 = al x bl */                       \
    if (STG) { STAGE_A((tt) + 1, 1 - (P), 0); STAGE_A((tt) + 1, 1 - (P), 2); }\
    _Pragma("unroll")                                                         \
    for (int m = 0; m < 4; ++m) { al0[m] = RD_A(bufT, m, c0);                 \
                                  al1[m] = RD_A(bufT, m, c1); }               \
    _Pragma("unroll")                                                         \
    for (int n = 0; n < 2; ++n) { bl0[n] = RD_B(bufT, n, c0);                 \
                                  bl1[n] = RD_B(bufT, n, c1); }               \
    BAR; PRIO1; MG(al0, bl0, 0, 0); MG(al1, bl1, 0, 0); PRIO0; BAR;           \
    /* ph2: stage B01(t+1); read bh; Q2 = al x bh; gate */                    \
    if (STG) { STAGE_B((tt) + 1, 1 - (P), 0); STAGE_B((tt) + 1, 1 - (P), 1); }\
    _Pragma("unroll")                                                         \
    for (int n = 0; n < 2; ++n) { bh0[n] = RD_B(bufT, 2 + n, c0);             \
                                  bh1[n] = RD_B(bufT, 2 + n, c1); }           \
    BAR; PRIO1; MG(al0, bh0, 0, 2); MG(al1, bh1, 0, 2); PRIO0;                \
    if ((G2) == 4) { VM4; }                                                   \
    if ((G2) == 0) { VM0; }                                                   \
    BAR;                                                                      \
    /* ph3: stage B23(t+1); read ah; Q3 = ah x bh */                          \
    if (STG) { STAGE_B((tt) + 1, 1 - (P), 2); STAGE_B((tt) + 1, 1 - (P), 3); }\
    _Pragma("unroll")                                                         \
    for (int m = 0; m < 4; ++m) { ah0[m] = RD_A(bufT, 4 + m, c0);             \
                                  ah1[m] = RD_A(bufT, 4 + m, c1); }           \
    BAR; PRIO1; MG(ah0, bh0, 4, 2); MG(ah1, bh1, 4, 2); PRIO0; BAR;           \
    /* ph4: stage A13(t+1); Q4 = ah x bl; gate; publish */                    \
    if (STG) { STAGE_A((tt) + 1, 1 - (P), 1); STAGE_A((tt) + 1, 1 - (P), 3); }\
    PRIO1; MG(ah0, bl0, 4, 0); MG(ah1, bl1, 4, 0); PRIO0;                     \
    if ((G4) == 2) { VM2; }                                                   \
    BAR;                                                                      \
  } while (0)

  // ---- Prologue: tile0's 4 region-pairs in read-order; retire all but A13(0)
  STAGE_A(0, 0, 0); STAGE_A(0, 0, 2);   // A02(0)
  STAGE_B(0, 0, 0); STAGE_B(0, 0, 1);   // B01(0)
  STAGE_B(0, 0, 2); STAGE_B(0, 0, 3);   // B23(0)
  STAGE_A(0, 0, 1); STAGE_A(0, 0, 3);   // A13(0)
  VM2;                                  // A02,B01,B23 landed; A13 in flight
  BAR;

  // ---- Main loop: tiles 0..61 (full pipeline), then 62 (stages 63), then 63
  #pragma unroll 1
  for (int t = 0; t < 62; t += 2) {
    TILE(0, t,     1, 4, 2);
    TILE(1, t + 1, 1, 4, 2);
  }
  TILE(0, 62, 1, 4, 2);
  TILE(1, 63, 0, 0, -1);   // edge: vmcnt(0) at end-ph2 retires A13(63)

  // Epilogue: acc * scales[col] + bias[col], fp32.
  // C/D frag: col = lane&15, row = (lane>>4)*4 + reg (m89-verified).
  const int crow = (lane >> 4) << 2;
  #pragma unroll
  for (int nf = 0; nf < 4; ++nf) {
    const int col = n0 + wn * 64 + nf * 16 + r16;
    const float s = scales[col];
    const float bb = bias[col];
    #pragma unroll
    for (int mf = 0; mf < 8; ++mf) {
      const int rb = m0 + wm * 128 + mf * 16 + crow;
      #pragma unroll
      for (int r = 0; r < 4; ++r)
        out[(size_t)(rb + r) * OUT_F + col] = acc[mf][nf][r] * s + bb;
    }
  }
#undef TILE
#undef MG
#undef RD_A
#undef RD_B
#undef STAGE_A
#undef STAGE_B
#undef GLD
}

// ---------------------------------------------------------------------------
// Fallback (only if ws too small): correct but slow fp32 path.
// ---------------------------------------------------------------------------
__global__ __launch_bounds__(256) void naive_kernel(
    const float* __restrict__ x, const int* __restrict__ codes,
    const float* __restrict__ cbs, const float* __restrict__ scales,
    const float* __restrict__ bias, float* __restrict__ out)
{
  __shared__ float xrow[IN_F];
  const int m = blockIdx.x;
  for (int i = threadIdx.x; i < IN_F; i += 256)
    xrow[i] = x[(size_t)m * IN_F + i];
  __syncthreads();
  for (int o = threadIdx.x; o < OUT_F; o += 256) {
    float acc = 0.f;
    const int2* crow = (const int2*)codes + (size_t)o * NIG;
    for (int g = 0; g < NIG; ++g) {
      const int2 c = crow[g];
      const float* e0 = cbs + (size_t)c.x * 8;
      const float* e1 = cbs + (size_t)CBSZ * 8 + (size_t)c.y * 8;
      const float* xr = xrow + g * 8;
      #pragma unroll
      for (int j = 0; j < 8; ++j) acc += (e0[j] + e1[j]) * xr[j];
    }
    out[(size_t)m * OUT_F + o] = acc * scales[o] + bias[o];
  }
}

// ---------------------------------------------------------------------------
extern "C" void kernel_launch(void* const* d_in, const int* in_sizes, int n_in,
                              void* d_out, int out_size, void* d_ws, size_t ws_size,
                              hipStream_t stream) {
  const float* x      = (const float*)d_in[0];
  const int*   codes  = (const int*)d_in[1];
  const float* cbs    = (const float*)d_in[2];
  const float* scales = (const float*)d_in[3];
  const float* bias   = (const float*)d_in[4];
  float* out = (float*)d_out;

  const size_t W_BYTES = (size_t)OUT_F * IN_F * sizeof(_Float16);  // 90.2 MB
  const size_t X_BYTES = (size_t)M_ROWS * IN_F * sizeof(_Float16); // 67.1 MB

  if (ws_size < W_BYTES + X_BYTES) {
    naive_kernel<<<M_ROWS, 256, 0, stream>>>(x, codes, cbs, scales, bias, out);
    return;
  }

  _Float16* W = (_Float16*)d_ws;
  _Float16* X = (_Float16*)((char*)d_ws + W_BYTES);

  dequant_w_kernel<<<(OUT_F * NIG) / 256, 256, 0, stream>>>(codes, cbs, W);
  convert_x_kernel<<<(M_ROWS * IN_F / 8) / 256, 256, 0, stream>>>(x, X);
  gemm_pipe<<<GRID_MT * GRID_NT, 512, 0, stream>>>(X, W, scales, bias, out);
}

// Round 10
// 815.679 us; speedup vs baseline: 1.8930x; 1.0029x over previous
//
#include <hip/hip_runtime.h>
#include <hip/hip_bf16.h>
#include <stdint.h>

// Problem constants (from reference)
#define IN_F 4096
#define OUT_F 11008
#define M_ROWS 8192              // 4 * 2048
#define NIG 512                  // IN_FEATURES / IN_GROUP(8)
#define CBSZ 256

typedef _Float16 f16x8 __attribute__((ext_vector_type(8)));
typedef float f32x4 __attribute__((ext_vector_type(4)));

// ---------------------------------------------------------------------------
// Kernel 1: dequantize W (UNSCALED: scales applied in GEMM epilogue in fp32).
// ---------------------------------------------------------------------------
__global__ __launch_bounds__(256) void dequant_w_kernel(
    const int* __restrict__ codes, const float* __restrict__ cbs,
    _Float16* __restrict__ W)
{
  const int idx = blockIdx.x * 256 + threadIdx.x;   // o*512 + g (exact grid)
  const int2 c = ((const int2*)codes)[idx];
  const float4* e0 = (const float4*)(cbs + (size_t)c.x * 8);
  const float4* e1 = (const float4*)(cbs + (size_t)CBSZ * 8 + (size_t)c.y * 8);
  const float4 a0 = e0[0], a1 = e0[1];
  const float4 b0 = e1[0], b1 = e1[1];
  f16x8 w;
  w[0] = (_Float16)(a0.x + b0.x);
  w[1] = (_Float16)(a0.y + b0.y);
  w[2] = (_Float16)(a0.z + b0.z);
  w[3] = (_Float16)(a0.w + b0.w);
  w[4] = (_Float16)(a1.x + b1.x);
  w[5] = (_Float16)(a1.y + b1.y);
  w[6] = (_Float16)(a1.z + b1.z);
  w[7] = (_Float16)(a1.w + b1.w);
  *(f16x8*)(W + (size_t)idx * 8) = w;
}

// ---------------------------------------------------------------------------
// Kernel 2: x fp32 -> f16, 8 elems/thread, vectorized.
// ---------------------------------------------------------------------------
__global__ __launch_bounds__(256) void convert_x_kernel(
    const float* __restrict__ x, _Float16* __restrict__ X)
{
  const size_t i = ((size_t)blockIdx.x * 256 + threadIdx.x) * 8;
  const float4 a = *(const float4*)(x + i);
  const float4 b = *(const float4*)(x + i + 4);
  f16x8 v;
  v[0] = (_Float16)a.x; v[1] = (_Float16)a.y;
  v[2] = (_Float16)a.z; v[3] = (_Float16)a.w;
  v[4] = (_Float16)b.x; v[5] = (_Float16)b.y;
  v[6] = (_Float16)b.z; v[7] = (_Float16)b.w;
  *(f16x8*)(X + i) = v;
}

// ---------------------------------------------------------------------------
// Kernel 3: 256x256x64 f16 GEMM — 4-phase same-phase schedule with
// m201-VERBATIM wait/fence placement (the one unreplicated m201 piece):
//   [ds_reads] [stages] [lgkmcnt(8) if 12 reads]
//   sched_barrier(0); s_barrier; lgkmcnt(0); sched_barrier(0);
//   setprio(1); 16 MFMA; setprio(0); [vmcnt gate]; s_barrier
// Rationale: reads stream DURING the barrier wait; sched_barrier fences stop
// hipcc from (a) emitting its counted lgkm wait BEFORE the barrier (which
// serializes read latency ahead of the sync) or (b) hoisting/sinking reads
// and MFMAs across the barrier (rule #18/#19 pathologies).
//
// Geometry/swizzle/staging/gates identical to r9 (all verified):
// 512 thr = 8 waves (2M x 4N), per-wave out 128x64; LDS 2x(A|B)[256][64] f16
// = 128 KB; swizzle chunk_lds = chunk ^ (row&7) (0 conflicts measured r4+);
// staging pre-permutes global source col, LDS dest linear.
// Phases per tile t (stages write buf^1 for t+1):
//   ph1: rd al(8),bl(4) | stg A02 | Q1=al*bl
//   ph2: rd bh(4)       | stg B01 | Q2=al*bh | vmcnt(4)
//   ph3: rd ah(8)       | stg B23 | Q3=ah*bh
//   ph4:                | stg A13 | Q4=ah*bl | vmcnt(2)
// Ledger (per-thread outstanding, invariant 2 entering ph1): ph1+2=4, ph2+2=6,
// end-ph2 vmcnt(4) retires A13(t) => ph3 ah safe; ph3+2=6... wait order:
// end-ph2 retires down to 4 = {A02,B01}(t+1) pending? Recount: entering ph1:
// {A13(t)}=2. ph1 +A02=4, ph2 +B01=6; vmcnt(4) retires A13(t) (oldest 2)
// => ph3's ah(t) reads safe (A13(t) landed). ph3 +B23=6, ph4 +A13=8;
// vmcnt(2) retires A02,B01,B23(t+1) => ph1/ph2(t+1) al,bl,bh reads safe
// (bl/bh span ALL B calls; both B01,B23 retired). Floor=2 until tile-63 edge.
// WAR: stages write regions whose last reads retired >=4 barriers earlier.
// ---------------------------------------------------------------------------
#define BM 256
#define BN 256
#define BK 64
#define NKT (IN_F / BK)          // 64
#define GRID_MT (M_ROWS / BM)    // 32
#define GRID_NT (OUT_F / BN)     // 43

__global__ __launch_bounds__(512, 2) void gemm_pipe(
    const _Float16* __restrict__ X, const _Float16* __restrict__ Wd,
    const float* __restrict__ scales, const float* __restrict__ bias,
    float* __restrict__ out)
{
  __shared__ char smem[131072];  // [2 bufs][A 32KB | B 32KB]

  // T1: XCD swizzle; nwg = 1376 % 8 == 0 -> simple form bijective
  const int cpx = (GRID_MT * GRID_NT) >> 3;        // 172
  const int wg = (blockIdx.x & 7) * cpx + (blockIdx.x >> 3);
  const int mt = wg & (GRID_MT - 1), nt = wg >> 5; // m-inner: same B-panel per XCD
  const int m0 = mt * BM, n0 = nt * BN;

  const int t_ = threadIdx.x;
  const int wave = t_ >> 6, lane = t_ & 63;
  const int wm = wave >> 2, wn = wave & 3;
  const int r16 = lane & 15;
  const int q = lane >> 4;                         // 16B piece within 64B k-half
  const int sw = r16 & 7;                          // row&7 (rows offset by mult of 16)
  const int c0 = ((q ^ sw) << 4);                  // swizzled chunk byte, k-half 0
  const int c1 = (((4 | q) ^ sw) << 4);            // swizzled chunk byte, k-half 1

  // Staging: thread t's 16B lands at linear LDS byte (call*8192 + t*16)
  //   -> row = call*64 + (t>>3), chunk_lds = t&7; logical chunk = (t&7)^((t>>3)&7)
  const int s_row0 = t_ >> 3;
  const int s_col  = (((t_ & 7) ^ ((t_ >> 3) & 7)) << 3);
  const _Float16* asrc = X  + (size_t)(m0 + s_row0) * IN_F + s_col;
  const _Float16* bsrc = Wd + (size_t)(n0 + s_row0) * IN_F + s_col;
  const int s_dst = wave * 1024;                   // wave-uniform; HW adds lane*16

  f32x4 acc[8][4] = {};
  // Same-phase fragments: no cross-tile carry, peak live set 64 VGPR
  f16x8 al0[4], al1[4], ah0[4], ah1[4], bl0[2], bl1[2], bh0[2], bh1[2];

#define GLD(gsrc, ldst) __builtin_amdgcn_global_load_lds(                     \
    (const __attribute__((address_space(1))) void*)(gsrc),                    \
    (__attribute__((address_space(3))) void*)(ldst), 16, 0, 0)
#define STAGE_A(kt, bufc, i) GLD(asrc + (size_t)(kt) * BK + (size_t)(i) * 64 * IN_F, \
    smem + (bufc) * 65536 + (i) * 8192 + s_dst)
#define STAGE_B(kt, bufc, i) GLD(bsrc + (size_t)(kt) * BK + (size_t)(i) * 64 * IN_F, \
    smem + (bufc) * 65536 + 32768 + (i) * 8192 + s_dst)

#define RD_A(bufp, mm, cc) (*(const f16x8*)((bufp) + ((wm * 128 + (mm) * 16 + r16) << 7) + (cc)))
#define RD_B(bufp, nn, cc) (*(const f16x8*)((bufp) + 32768 + ((wn * 64 + (nn) * 16 + r16) << 7) + (cc)))

#define BAR   __builtin_amdgcn_s_barrier()
#define PRIO1 __builtin_amdgcn_s_setprio(1)
#define PRIO0 __builtin_amdgcn_s_setprio(0)
#define SBAR0 __builtin_amdgcn_sched_barrier(0)
#define LGKM0 asm volatile("s_waitcnt lgkmcnt(0)" ::: "memory")
#define LGKM8 asm volatile("s_waitcnt lgkmcnt(8)" ::: "memory")
#define VM4 asm volatile("s_waitcnt vmcnt(4)" ::: "memory")
#define VM2 asm volatile("s_waitcnt vmcnt(2)" ::: "memory")
#define VM0 asm volatile("s_waitcnt vmcnt(0)" ::: "memory")

// 8-MFMA group: 4 m-frags x 2 n-frags into acc[MO..][NO..]
#define MG(AF, BF, MO, NO)                                                    \
    _Pragma("unroll")                                                         \
    for (int m = 0; m < 4; ++m)                                               \
      _Pragma("unroll")                                                       \
      for (int n = 0; n < 2; ++n)                                             \
        acc[(MO) + m][(NO) + n] = __builtin_amdgcn_mfma_f32_16x16x32_f16(     \
            AF[m], BF[n], acc[(MO) + m][(NO) + n], 0, 0, 0)

// One K-tile, 4 phases, m201-verbatim fences. P: parity. STG: stage t+1.
// G2: end-ph2 gate (4 normal, 0 tail). G4: end-ph4 gate (2 normal, -1 none).
#define TILE(P, tt, STG, G2, G4) do {                                         \
    const char* bufT = smem + (P) * 65536;                                    \
    /* ph1: rd al,bl (12); stg A02; Q1 = al x bl */                           \
    _Pragma("unroll")                                                         \
    for (int m = 0; m < 4; ++m) { al0[m] = RD_A(bufT, m, c0);                 \
                                  al1[m] = RD_A(bufT, m, c1); }               \
    _Pragma("unroll")                                                         \
    for (int n = 0; n < 2; ++n) { bl0[n] = RD_B(bufT, n, c0);                 \
                                  bl1[n] = RD_B(bufT, n, c1); }               \
    if (STG) { STAGE_A((tt) + 1, 1 - (P), 0); STAGE_A((tt) + 1, 1 - (P), 2); }\
    LGKM8;                                                                    \
    SBAR0; BAR; LGKM0; SBAR0;                                                 \
    PRIO1; MG(al0, bl0, 0, 0); MG(al1, bl1, 0, 0); PRIO0; SBAR0; BAR;         \
    /* ph2: rd bh (4); stg B01; Q2 = al x bh; gate */                         \
    _Pragma("unroll")                                                         \
    for (int n = 0; n < 2; ++n) { bh0[n] = RD_B(bufT, 2 + n, c0);             \
                                  bh1[n] = RD_B(bufT, 2 + n, c1); }           \
    if (STG) { STAGE_B((tt) + 1, 1 - (P), 0); STAGE_B((tt) + 1, 1 - (P), 1); }\
    SBAR0; BAR; LGKM0; SBAR0;                                                 \
    PRIO1; MG(al0, bh0, 0, 2); MG(al1, bh1, 0, 2); PRIO0; SBAR0;              \
    if ((G2) == 4) { VM4; }                                                   \
    if ((G2) == 0) { VM0; }                                                   \
    BAR;                                                                      \
    /* ph3: rd ah (8); stg B23; Q3 = ah x bh */                               \
    _Pragma("unroll")                                                         \
    for (int m = 0; m < 4; ++m) { ah0[m] = RD_A(bufT, 4 + m, c0);             \
                                  ah1[m] = RD_A(bufT, 4 + m, c1); }           \
    if (STG) { STAGE_B((tt) + 1, 1 - (P), 2); STAGE_B((tt) + 1, 1 - (P), 3); }\
    SBAR0; BAR; LGKM0; SBAR0;                                                 \
    PRIO1; MG(ah0, bh0, 4, 2); MG(ah1, bh1, 4, 2); PRIO0; SBAR0; BAR;         \
    /* ph4: stg A13; Q4 = ah x bl (no reads, no lgkm wait); gate; publish */  \
    if (STG) { STAGE_A((tt) + 1, 1 - (P), 1); STAGE_A((tt) + 1, 1 - (P), 3); }\
    SBAR0;                                                                    \
    PRIO1; MG(ah0, bl0, 4, 0); MG(ah1, bl1, 4, 0); PRIO0; SBAR0;              \
    if ((G4) == 2) { VM2; }                                                   \
    BAR;                                                                      \
  } while (0)

  // ---- Prologue: tile0's 4 region-pairs in read-order; retire all but A13(0)
  STAGE_A(0, 0, 0); STAGE_A(0, 0, 2);   // A02(0)
  STAGE_B(0, 0, 0); STAGE_B(0, 0, 1);   // B01(0)
  STAGE_B(0, 0, 2); STAGE_B(0, 0, 3);   // B23(0)
  STAGE_A(0, 0, 1); STAGE_A(0, 0, 3);   // A13(0)
  SBAR0; VM2;                           // A02,B01,B23 landed; A13 in flight
  BAR;

  // ---- Main loop: tiles 0..61 (full pipeline), then 62 (stages 63), then 63
  #pragma unroll 1
  for (int t = 0; t < 62; t += 2) {
    TILE(0, t,     1, 4, 2);
    TILE(1, t + 1, 1, 4, 2);
  }
  TILE(0, 62, 1, 4, 2);
  TILE(1, 63, 0, 0, -1);   // edge: vmcnt(0) at end-ph2 retires A13(63)

  // Epilogue: acc * scales[col] + bias[col], fp32.
  // C/D frag: col = lane&15, row = (lane>>4)*4 + reg (m89-verified).
  const int crow = (lane >> 4) << 2;
  #pragma unroll
  for (int nf = 0; nf < 4; ++nf) {
    const int col = n0 + wn * 64 + nf * 16 + r16;
    const float s = scales[col];
    const float bb = bias[col];
    #pragma unroll
    for (int mf = 0; mf < 8; ++mf) {
      const int rb = m0 + wm * 128 + mf * 16 + crow;
      #pragma unroll
      for (int r = 0; r < 4; ++r)
        out[(size_t)(rb + r) * OUT_F + col] = acc[mf][nf][r] * s + bb;
    }
  }
#undef TILE
#undef MG
#undef RD_A
#undef RD_B
#undef STAGE_A
#undef STAGE_B
#undef GLD
}

// ---------------------------------------------------------------------------
// Fallback (only if ws too small): correct but slow fp32 path.
// ---------------------------------------------------------------------------
__global__ __launch_bounds__(256) void naive_kernel(
    const float* __restrict__ x, const int* __restrict__ codes,
    const float* __restrict__ cbs, const float* __restrict__ scales,
    const float* __restrict__ bias, float* __restrict__ out)
{
  __shared__ float xrow[IN_F];
  const int m = blockIdx.x;
  for (int i = threadIdx.x; i < IN_F; i += 256)
    xrow[i] = x[(size_t)m * IN_F + i];
  __syncthreads();
  for (int o = threadIdx.x; o < OUT_F; o += 256) {
    float acc = 0.f;
    const int2* crow = (const int2*)codes + (size_t)o * NIG;
    for (int g = 0; g < NIG; ++g) {
      const int2 c = crow[g];
      const float* e0 = cbs + (size_t)c.x * 8;
      const float* e1 = cbs + (size_t)CBSZ * 8 + (size_t)c.y * 8;
      const float* xr = xrow + g * 8;
      #pragma unroll
      for (int j = 0; j < 8; ++j) acc += (e0[j] + e1[j]) * xr[j];
    }
    out[(size_t)m * OUT_F + o] = acc * scales[o] + bias[o];
  }
}

// ---------------------------------------------------------------------------
extern "C" void kernel_launch(void* const* d_in, const int* in_sizes, int n_in,
                              void* d_out, int out_size, void* d_ws, size_t ws_size,
                              hipStream_t stream) {
  const float* x      = (const float*)d_in[0];
  const int*   codes  = (const int*)d_in[1];
  const float* cbs    = (const float*)d_in[2];
  const float* scales = (const float*)d_in[3];
  const float* bias   = (const float*)d_in[4];
  float* out = (float*)d_out;

  const size_t W_BYTES = (size_t)OUT_F * IN_F * sizeof(_Float16);  // 90.2 MB
  const size_t X_BYTES = (size_t)M_ROWS * IN_F * sizeof(_Float16); // 67.1 MB

  if (ws_size < W_BYTES + X_BYTES) {
    naive_kernel<<<M_ROWS, 256, 0, stream>>>(x, codes, cbs, scales, bias, out);
    return;
  }

  _Float16* W = (_Float16*)d_ws;
  _Float16* X = (_Float16*)((char*)d_ws + W_BYTES);

  dequant_w_kernel<<<(OUT_F * NIG) / 256, 256, 0, stream>>>(codes, cbs, W);
  convert_x_kernel<<<(M_ROWS * IN_F / 8) / 256, 256, 0, stream>>>(x, X);
  gemm_pipe<<<GRID_MT * GRID_NT, 512, 0, stream>>>(X, W, scales, bias, out);
}